// Round 6
// baseline (482.246 us; speedup 1.0000x reference)
//
#include <hip/hip_runtime.h>
#include <stdint.h>

#define B_ 128
#define T_ 1024
#define H_ 512
#define A_ 256
#define G_ 2128

typedef short s16x8 __attribute__((ext_vector_type(8)));
typedef float f32x4 __attribute__((ext_vector_type(4)));
typedef unsigned int u32;

__device__ inline unsigned short f2bf(float f) {
  unsigned u = __float_as_uint(f);
  u += 0x7fff + ((u >> 16) & 1);   // round-to-nearest-even
  return (unsigned short)(u >> 16);
}
__device__ inline unsigned pack2bf(float a, float b) {
  return ((unsigned)f2bf(b) << 16) | f2bf(a);
}
__device__ inline float fast_tanh(float x) {
  x = fminf(15.f, fmaxf(-15.f, x));
  float e = __expf(2.f * x);
  return (e - 1.f) * __builtin_amdgcn_rcpf(e + 1.f);
}
// async global->LDS, 16B per lane; LDS dest = uniform base + lane*16
__device__ inline void gl_lds16(const void* g, void* l) {
  __builtin_amdgcn_global_load_lds(
      (const __attribute__((address_space(1))) u32*)g,
      (__attribute__((address_space(3))) u32*)l, 16, 0, 0);
}

// K^T bf16 tiled [kb][a][k'], 16B-group swizzle baked: group g of row a at g^(a&3).
__global__ void prep_kt(const float* __restrict__ K,
                        unsigned short* __restrict__ khi) {
  int idx = blockIdx.x * 256 + threadIdx.x;   // h*256 + a
  int h = idx >> 8;
  int a = idx & 255;
  int kb = h >> 5, k = h & 31;
  int grp = k >> 3, sub = k & 7;
  khi[kb * 8192 + a * 32 + ((grp ^ (a & 3)) * 8) + sub] = f2bf(K[idx]);
}

// gp4[gc][b][a] = partial of w0 * sum_g genes[b,g]*Wg[g,a]; gc==0 adds biases.
__global__ __launch_bounds__(256) void gene_proj_k(
    const float* __restrict__ genes, const float* __restrict__ w0p,
    const float* __restrict__ Wg, const float* __restrict__ bg,
    const float* __restrict__ db, float* __restrict__ gp4) {
  __shared__ float sg[532];
  int b = blockIdx.x;
  int gc = blockIdx.y;          // 0..3 chunks of 532
  int a = threadIdx.x;
  int g0 = gc * 532;
  for (int i = threadIdx.x; i < 532; i += 256) sg[i] = genes[(size_t)b * G_ + g0 + i];
  __syncthreads();
  float s = 0.f;
  #pragma unroll 8
  for (int g = 0; g < 532; ++g)
    s = fmaf(sg[g], Wg[(size_t)(g0 + g) * A_ + a], s);
  float val = w0p[0] * s;
  if (gc == 0) val += bg[a] + db[a];
  gp4[(gc * B_ + b) * A_ + a] = val;
}

// Fused, 64-row tiles, DOUBLE-BUFFERED single-barrier K-loop.
// Per (b, tb in 0..15):
//   phase A: GEMM proj = smiles_tile @ K  (64t x 256a), K=512 in 16 steps
//   phase B: xv = sum_a v*tanh(gp+proj); local softmax partial (m,l,p)
//   phase C: outp[tb][h] = sum_t p[t]*smiles[t,h] (fp32 re-read, L2/L3-hot)
// K-loop ledger (uniform): each iter kb<15 issues [gl_lds16 x4][A-pref x2];
// top-of-iter "s_waitcnt vmcnt(2)" retires the PREVIOUS iter's 4 gl_lds16
// (they had a full MFMA phase to land) and leaves the 2 A-prefetches in
// flight. One s_barrier per iter; writer-side lgkmcnt(0) before it keeps the
// cross-wave sA RAW ordering. kb=14 issues dead prefetches to keep the
// ledger uniform so vmcnt(2) is exact at kb=15.
__global__ __launch_bounds__(256, 3) void fused1(
    const float* __restrict__ smiles, const unsigned short* __restrict__ khi,
    const float* __restrict__ gp4, const float* __restrict__ v,
    float* __restrict__ xv, float* __restrict__ ml, float* __restrict__ outp) {
  __shared__ unsigned short sA[2][64 * 32];    // 2 x 4 KB
  __shared__ unsigned short sB[2][256 * 32];   // 2 x 16 KB
  __shared__ float sXV[64 * 4];                // 1 KB
  __shared__ float sP[64];

  const int tid = threadIdx.x;
  const int b = blockIdx.y;
  const int tb = blockIdx.x;                // 0..15 (64-t tiles)
  const int lane = tid & 63;
  const int w = tid >> 6;
  const int n = lane & 15;
  const int q = lane >> 4;

  // A staging: thread -> row ar (0..63), 8-float group g8 (0..3)
  const int ar = tid >> 2;
  const int g8 = tid & 3;
  const int s0 = (g8 ^ (ar & 3)) * 8;       // swizzled 16B-group slot
  const float* asrc = smiles + ((size_t)(b * 1024 + tb * 64 + ar)) * 512 + g8 * 8;

  f32x4 acc[4][4];
  #pragma unroll
  for (int i = 0; i < 4; ++i)
    #pragma unroll
    for (int j = 0; j < 4; ++j)
      acc[i][j] = (f32x4){0.f, 0.f, 0.f, 0.f};

  // ---- prologue: stage chunk 0 into buf 0, prefetch chunk 1 ----
  float4 f0 = *reinterpret_cast<const float4*>(asrc);
  float4 f1 = *reinterpret_cast<const float4*>(asrc + 4);
  {
    uint4 p0;
    p0.x = pack2bf(f0.x, f0.y); p0.y = pack2bf(f0.z, f0.w);
    p0.z = pack2bf(f1.x, f1.y); p0.w = pack2bf(f1.z, f1.w);
    *reinterpret_cast<uint4*>(&sA[0][ar * 32 + s0]) = p0;
    #pragma unroll
    for (int r = 0; r < 4; ++r)
      gl_lds16(khi + w * 2048 + r * 512 + lane * 8, &sB[0][w * 2048 + r * 512]);
    f0 = *reinterpret_cast<const float4*>(asrc + 32);
    f1 = *reinterpret_cast<const float4*>(asrc + 32 + 4);
    asm volatile("s_waitcnt lgkmcnt(0)" ::: "memory");
    __builtin_amdgcn_sched_barrier(0);
    __builtin_amdgcn_s_barrier();
    __builtin_amdgcn_sched_barrier(0);
  }
  // outstanding vm: [gl_lds x4, pref x2]  (steady-state entry condition)

  const int sw = (q ^ (n & 3)) * 8;
  for (int kb = 0; kb < 16; ++kb) {
    const int cur = kb & 1;
    const int nxt = cur ^ 1;
    // retire prev iter's 4 gl_lds16 -> sB[cur] ready; 2 A-prefs stay in flight
    asm volatile("s_waitcnt vmcnt(2)" ::: "memory");
    __builtin_amdgcn_sched_barrier(0);

    // frag reads from cur buffers (issue early; overlap with staging)
    s16x8 af[4], bh[4];
    #pragma unroll
    for (int j = 0; j < 4; ++j)
      bh[j] = *reinterpret_cast<const s16x8*>(&sB[cur][(w * 64 + j * 16 + n) * 32 + sw]);
    #pragma unroll
    for (int i = 0; i < 4; ++i)
      af[i] = *reinterpret_cast<const s16x8*>(&sA[cur][(i * 16 + n) * 32 + sw]);

    if (kb < 15) {
      // pack chunk kb+1 (f regs; compiler inserts the vmcnt wait for them)
      uint4 p0;
      p0.x = pack2bf(f0.x, f0.y); p0.y = pack2bf(f0.z, f0.w);
      p0.z = pack2bf(f1.x, f1.y); p0.w = pack2bf(f1.z, f1.w);
      *reinterpret_cast<uint4*>(&sA[nxt][ar * 32 + s0]) = p0;
      // vm ops 1-4: stage B chunk kb+1
      #pragma unroll
      for (int r = 0; r < 4; ++r)
        gl_lds16(khi + (kb + 1) * 8192 + w * 2048 + r * 512 + lane * 8,
                 &sB[nxt][w * 2048 + r * 512]);
      // vm ops 5-6: prefetch chunk kb+2 (kb=14: dead re-read keeps ledger uniform)
      int noff = (kb < 14) ? (kb + 2) * 32 : 15 * 32;
      f0 = *reinterpret_cast<const float4*>(asrc + noff);
      f1 = *reinterpret_cast<const float4*>(asrc + noff + 4);
    }

    #pragma unroll
    for (int i = 0; i < 4; ++i)
      #pragma unroll
      for (int j = 0; j < 4; ++j)
        acc[i][j] = __builtin_amdgcn_mfma_f32_16x16x32_bf16(af[i], bh[j], acc[i][j], 0, 0, 0);

    // own ds_write (sA[nxt]) complete before the barrier -> next iter's
    // cross-wave reads are safe.
    asm volatile("s_waitcnt lgkmcnt(0)" ::: "memory");
    __builtin_amdgcn_sched_barrier(0);
    __builtin_amdgcn_s_barrier();
    __builtin_amdgcn_sched_barrier(0);
  }

  // epilogue: sum_a v_a * tanh(gp + proj); D: t = i*16 + q*4+r, a = w*64+j*16+n
  float vv[4], gg[4];
  #pragma unroll
  for (int j = 0; j < 4; ++j) {
    int a = w * 64 + j * 16 + n;
    int idx = b * A_ + a;
    vv[j] = v[a];
    gg[j] = gp4[idx] + gp4[B_ * A_ + idx] + gp4[2 * B_ * A_ + idx] +
            gp4[3 * B_ * A_ + idx];
  }
  #pragma unroll
  for (int i = 0; i < 4; ++i) {
    #pragma unroll
    for (int r = 0; r < 4; ++r) {
      float s = 0.f;
      #pragma unroll
      for (int j = 0; j < 4; ++j)
        s += vv[j] * fast_tanh(acc[i][j][r] + gg[j]);
      s += __shfl_xor(s, 1); s += __shfl_xor(s, 2);
      s += __shfl_xor(s, 4); s += __shfl_xor(s, 8);
      if (n == 0) sXV[(i * 16 + q * 4 + r) * 4 + w] = s;
    }
  }
  __syncthreads();

  // phase B: wave 0 owns the tile's 64 xv values; local softmax partial
  if (w == 0) {
    float* p = &sXV[lane * 4];
    float xvv = p[0] + p[1] + p[2] + p[3];
    xv[(size_t)b * T_ + tb * 64 + lane] = xvv;     // raw, for final alphas
    float mx = xvv;
    #pragma unroll
    for (int o = 1; o < 64; o <<= 1) mx = fmaxf(mx, __shfl_xor(mx, o));
    float e = __expf(xvv - mx);
    sP[lane] = e;
    float lsum = e;
    #pragma unroll
    for (int o = 1; o < 64; o <<= 1) lsum += __shfl_xor(lsum, o);
    if (lane == 0) {
      ml[(b * 16 + tb) * 2] = mx;
      ml[(b * 16 + tb) * 2 + 1] = lsum;
    }
  }
  __syncthreads();

  // phase C: outp[h] = sum_t p[t] * smiles[b, tile_t, h]; 2 h-cols per thread.
  float2 a2 = {0.f, 0.f};
  const float* sm2 = smiles + ((size_t)(b * 1024 + tb * 64)) * 512 + tid * 2;
  #pragma unroll 8
  for (int t = 0; t < 64; ++t) {
    float a = sP[t];
    float2 sv = *reinterpret_cast<const float2*>(sm2 + (size_t)t * 512);
    a2.x = fmaf(a, sv.x, a2.x);
    a2.y = fmaf(a, sv.y, a2.y);
  }
  *reinterpret_cast<float2*>(outp + ((size_t)(b * 16 + tb)) * 512 + tid * 2) = a2;
}

// merge: per b combine 16 tile partials (log-sum-exp), write out + alphas.
__global__ __launch_bounds__(256) void merge_k(
    const float* __restrict__ ml, const float* __restrict__ outp,
    const float* __restrict__ xv, float* __restrict__ out,
    float* __restrict__ alphas) {
  int b = blockIdx.x, tid = threadIdx.x;
  float m[16], lq[16];
  float M = -1e30f;
  #pragma unroll
  for (int t = 0; t < 16; ++t) {
    m[t] = ml[(b * 16 + t) * 2];
    lq[t] = ml[(b * 16 + t) * 2 + 1];
    M = fmaxf(M, m[t]);
  }
  float L = 0.f, wq[16];
  #pragma unroll
  for (int t = 0; t < 16; ++t) {
    wq[t] = __expf(m[t] - M);
    L = fmaf(lq[t], wq[t], L);
  }
  float invL = 1.f / L;
  float2 o2 = {0.f, 0.f};
  #pragma unroll
  for (int t = 0; t < 16; ++t) {
    float2 p = *reinterpret_cast<const float2*>(outp + ((size_t)(b * 16 + t)) * 512 + tid * 2);
    o2.x = fmaf(wq[t], p.x, o2.x);
    o2.y = fmaf(wq[t], p.y, o2.y);
  }
  o2.x *= invL; o2.y *= invL;
  *reinterpret_cast<float2*>(out + (size_t)b * H_ + tid * 2) = o2;
  #pragma unroll
  for (int t = tid; t < T_; t += 256)
    alphas[(size_t)b * T_ + t] = __expf(xv[(size_t)b * T_ + t] - M) * invL;
}

extern "C" void kernel_launch(void* const* d_in, const int* in_sizes, int n_in,
                              void* d_out, int out_size, void* d_ws, size_t ws_size,
                              hipStream_t stream) {
  const float* genes  = (const float*)d_in[0];
  const float* smiles = (const float*)d_in[1];
  const float* w0     = (const float*)d_in[2];
  const float* wg     = (const float*)d_in[3];
  const float* bg     = (const float*)d_in[4];
  const float* dk     = (const float*)d_in[5];
  const float* db     = (const float*)d_in[6];
  const float* v      = (const float*)d_in[7];
  float* out = (float*)d_out;            // [B,H] output then [B,T] alphas
  char* ws = (char*)d_ws;
  float* gp4 = (float*)ws;                                   // 512 KB (4 partials)
  unsigned short* khi = (unsigned short*)(ws + 524288);      // 256 KB
  float* xv   = (float*)(ws + 786432);                       // 512 KB raw energies
  float* ml   = (float*)(ws + 1310720);                      // 16 KB (m,l per tile)
  float* outp = (float*)(ws + 1327104);                      // 4 MB partial outputs
  float* alphas = out + B_ * H_;

  prep_kt<<<512, 256, 0, stream>>>(dk, khi);
  gene_proj_k<<<dim3(B_, 4), 256, 0, stream>>>(genes, w0, wg, bg, db, gp4);
  fused1<<<dim3(16, B_), 256, 0, stream>>>(smiles, khi, gp4, v, xv, ml, outp);
  merge_k<<<B_, 256, 0, stream>>>(ml, outp, xv, out, alphas);
}